// Round 6
// baseline (1079.484 us; speedup 1.0000x reference)
//
#include <hip/hip_runtime.h>

// GATv2 stack on MI355X. fp32 throughout (no fp32 MFMA on CDNA4 -> vector ALU).
// R5: half-channel gat dispatches (hot xl slice 3.2MB -> fits 4MB per-XCD L2);
// each wave processes 2 edges (one per 32-lane half), online-softmax state
// merged across halves via shfl_xor(32). Streaming csr/xr loads nontemporal.

static __device__ __forceinline__ float lrelu(float x, float s) {
    return x > 0.f ? x : s * x;
}

// ---------------- graph build ----------------

__global__ void k_degree(const int* __restrict__ dst, int* __restrict__ cnt,
                         int* __restrict__ rank, int E) {
    int e = blockIdx.x * blockDim.x + threadIdx.x;
    if (e >= E) return;
    rank[e] = atomicAdd(&cnt[dst[e]], 1);
}

__launch_bounds__(1024)
__global__ void k_rowptr(const int* __restrict__ cnt, int* __restrict__ row_ptr, int n) {
    __shared__ int tot[1024];
    int t = threadIdx.x;
    int chunk = (n + 1023) >> 10;
    int b = min(t * chunk, n), e = min(b + chunk, n);
    int s = 0;
    for (int i = b; i < e; ++i) s += cnt[i] + 1;
    tot[t] = s;
    __syncthreads();
    for (int off = 1; off < 1024; off <<= 1) {
        int v = (t >= off) ? tot[t - off] : 0;
        __syncthreads();
        tot[t] += v;
        __syncthreads();
    }
    int run = (t > 0) ? tot[t - 1] : 0;
    for (int i = b; i < e; ++i) { row_ptr[i] = run; run += cnt[i] + 1; }
    if (t == 1023) row_ptr[n] = run;
}

__global__ void k_scatter(const int* __restrict__ src, const int* __restrict__ dst,
                          const float* __restrict__ ea, const int* __restrict__ rank,
                          const int* __restrict__ row_ptr,
                          int* __restrict__ csr_src, float* __restrict__ csr_ea, int E) {
    int e = blockIdx.x * blockDim.x + threadIdx.x;
    if (e >= E) return;
    int pos = row_ptr[dst[e]] + rank[e];
    csr_src[pos] = src[e];
    csr_ea[2 * (size_t)pos] = ea[2 * (size_t)e];
    csr_ea[2 * (size_t)pos + 1] = ea[2 * (size_t)e + 1];
}

__global__ void k_selfloop(const int* __restrict__ row_ptr,
                           int* __restrict__ csr_src, float* __restrict__ csr_ea, int n) {
    int i = blockIdx.x * blockDim.x + threadIdx.x;
    if (i >= n) return;
    int p0 = row_ptr[i], p1 = row_ptr[i + 1];
    float s0 = 0.f, s1 = 0.f;
    for (int p = p0; p < p1 - 1; ++p) {
        s0 += csr_ea[2 * (size_t)p];
        s1 += csr_ea[2 * (size_t)p + 1];
    }
    float c = fmaxf((float)(p1 - 1 - p0), 1.f);
    csr_src[p1 - 1] = i;
    csr_ea[2 * (size_t)(p1 - 1)] = s0 / c;
    csr_ea[2 * (size_t)(p1 - 1) + 1] = s1 / c;
}

// ---------------- projections ----------------

__global__ void k_proj0(const float* __restrict__ x,
                        const float* __restrict__ Wl, const float* __restrict__ bl,
                        const float* __restrict__ Wr, const float* __restrict__ br,
                        float* __restrict__ xl, float* __restrict__ xr, int n) {
    int idx = blockIdx.x * blockDim.x + threadIdx.x;
    if (idx >= n * 64) return;
    int i = idx >> 6, c = idx & 63;
    float x0 = x[2 * i], x1 = x[2 * i + 1];
    xl[idx] = x0 * Wl[c] + x1 * Wl[64 + c] + bl[c];
    xr[idx] = x0 * Wr[c] + x1 * Wr[64 + c] + br[c];
}

// h[N,64] @ {Wl,Wr}[64,64] + {bl,br} in ONE pass (h read once).
__launch_bounds__(256)
__global__ void k_proj64(const float* __restrict__ h,
                         const float* __restrict__ Wl, const float* __restrict__ bl,
                         const float* __restrict__ Wr, const float* __restrict__ br,
                         float* __restrict__ xl, float* __restrict__ xr, int n) {
    __shared__ float wsl[4096], wsr[4096];
    int t = threadIdx.x;
    for (int i = t; i < 4096; i += 256) { wsl[i] = Wl[i]; wsr[i] = Wr[i]; }
    __syncthreads();
    int rg = t >> 2, cg = (t & 3) << 4;
    int r0 = blockIdx.x * 128 + rg * 2;
    float accl[2][16], accr[2][16];
#pragma unroll
    for (int r = 0; r < 2; ++r)
#pragma unroll
        for (int j = 0; j < 16; ++j) { accl[r][j] = 0.f; accr[r][j] = 0.f; }
    for (int k0 = 0; k0 < 64; k0 += 4) {
        float hk[2][4];
#pragma unroll
        for (int r = 0; r < 2; ++r) {
            int gr = r0 + r;
            float4 v = (gr < n) ? *(const float4*)(h + (size_t)gr * 64 + k0)
                                : make_float4(0.f, 0.f, 0.f, 0.f);
            hk[r][0] = v.x; hk[r][1] = v.y; hk[r][2] = v.z; hk[r][3] = v.w;
        }
#pragma unroll
        for (int kk = 0; kk < 4; ++kk) {
            const float* wl = wsl + (k0 + kk) * 64 + cg;
            const float* wr = wsr + (k0 + kk) * 64 + cg;
#pragma unroll
            for (int r = 0; r < 2; ++r)
#pragma unroll
                for (int j = 0; j < 16; ++j) {
                    accl[r][j] += hk[r][kk] * wl[j];
                    accr[r][j] += hk[r][kk] * wr[j];
                }
        }
    }
#pragma unroll
    for (int r = 0; r < 2; ++r) {
        int gr = r0 + r;
        if (gr < n) {
            float* ol = xl + (size_t)gr * 64 + cg;
            float* orr = xr + (size_t)gr * 64 + cg;
#pragma unroll
            for (int j = 0; j < 16; ++j) {
                ol[j] = accl[r][j] + bl[cg + j];
                orr[j] = accr[r][j] + br[cg + j];
            }
        }
    }
}

// final projections fused: packed[i][0:16)=f_xl, [16:32)=s_xl, [32:48)=f_xr, [48:64)=s_xr
__launch_bounds__(256)
__global__ void k_proj_final(const float* __restrict__ h,
                             const float* __restrict__ fWl, const float* __restrict__ fbl,
                             const float* __restrict__ fWr, const float* __restrict__ fbr,
                             const float* __restrict__ sWl, const float* __restrict__ sbl,
                             const float* __restrict__ sWr, const float* __restrict__ sbr,
                             float* __restrict__ packed, int n) {
    __shared__ float ws[4096];
    __shared__ float bs[64];
    int t = threadIdx.x;
    for (int i = t; i < 1024; i += 256) {
        int k = i >> 4, j = i & 15;
        ws[k * 64 + j] = fWl[i];
        ws[k * 64 + 16 + j] = sWl[i];
        ws[k * 64 + 32 + j] = fWr[i];
        ws[k * 64 + 48 + j] = sWr[i];
    }
    if (t < 16) { bs[t] = fbl[t]; bs[16 + t] = sbl[t]; bs[32 + t] = fbr[t]; bs[48 + t] = sbr[t]; }
    __syncthreads();
    int rg = t >> 2, cg = (t & 3) << 4;
    int r0 = blockIdx.x * 256 + rg * 4;
    float acc[4][16];
#pragma unroll
    for (int r = 0; r < 4; ++r)
#pragma unroll
        for (int j = 0; j < 16; ++j) acc[r][j] = 0.f;
    for (int k0 = 0; k0 < 64; k0 += 4) {
        float hk[4][4];
#pragma unroll
        for (int r = 0; r < 4; ++r) {
            int gr = r0 + r;
            float4 v = (gr < n) ? *(const float4*)(h + (size_t)gr * 64 + k0)
                                : make_float4(0.f, 0.f, 0.f, 0.f);
            hk[r][0] = v.x; hk[r][1] = v.y; hk[r][2] = v.z; hk[r][3] = v.w;
        }
#pragma unroll
        for (int kk = 0; kk < 4; ++kk) {
            const float* wrow = ws + (k0 + kk) * 64 + cg;
#pragma unroll
            for (int r = 0; r < 4; ++r)
#pragma unroll
                for (int j = 0; j < 16; ++j) acc[r][j] += hk[r][kk] * wrow[j];
        }
    }
#pragma unroll
    for (int r = 0; r < 4; ++r) {
        int gr = r0 + r;
        if (gr < n) {
            float* o = packed + (size_t)gr * 64 + cg;
#pragma unroll
            for (int j = 0; j < 16; ++j) o[j] = acc[r][j] + bs[cg + j];
        }
    }
}

// ---------------- GATv2 attention, half-channel dispatch ----------------
// one wave per dst node, channels [co, co+32). lane = 32*eh + ch: the two
// 32-lane halves process different edges of the same dst; online-softmax
// state merged across halves at the end via shfl_xor(32).
__launch_bounds__(256)
__global__ void k_gat_h(const float* __restrict__ xl, const float* __restrict__ xr,
                        const int* __restrict__ row_ptr, const int* __restrict__ csr_src,
                        const float* __restrict__ csr_ea,
                        const float* __restrict__ We,   // [2,64]
                        const float* __restrict__ att,  // [16,4] flat = [64]
                        const float* __restrict__ bias, // [64]
                        float* __restrict__ out, int n, int relu, int co) {
    int wave = (blockIdx.x * blockDim.x + threadIdx.x) >> 6;
    int lane = threadIdx.x & 63;
    if (wave >= n) return;
    const int d = wave;
    const int eh = lane >> 5;        // edge slot within wave
    const int ch = lane & 31;        // channel within half
    const int c = co + ch;           // global channel
    const int p0 = __builtin_amdgcn_readfirstlane(row_ptr[d]);
    const int p1 = __builtin_amdgcn_readfirstlane(row_ptr[d + 1]);
    const float we0 = We[c], we1 = We[64 + c];
    const float av = att[c];
    const float xrv = __builtin_nontemporal_load(xr + (size_t)d * 64 + c);

    float mx = -3.0e38f, den = 0.f, acc = 0.f;

    auto step = [&](float xv, float e0, float e1, bool valid) {
        float tv = lrelu(xv + xrv + e0 * we0 + e1 * we1, 0.2f) * av;
        tv += __shfl_xor(tv, 1);
        tv += __shfl_xor(tv, 2);     // quad sum -> per-head logit
        if (!valid) tv = -__builtin_inff();
        float nm = fmaxf(mx, tv);
        float sc = __expf(mx - nm), w = __expf(tv - nm);
        den = den * sc + w;
        acc = acc * sc + w * xv;
        mx = nm;
    };

    for (int p = p0; p < p1; p += 4) {
        int qa = p + eh, qb = p + 2 + eh;
        int qac = min(qa, p1 - 1), qbc = min(qb, p1 - 1);
        int sa = __builtin_nontemporal_load(csr_src + qac);
        int sb = __builtin_nontemporal_load(csr_src + qbc);
        float ea0 = __builtin_nontemporal_load(csr_ea + 2 * (size_t)qac);
        float ea1 = __builtin_nontemporal_load(csr_ea + 2 * (size_t)qac + 1);
        float eb0 = __builtin_nontemporal_load(csr_ea + 2 * (size_t)qbc);
        float eb1 = __builtin_nontemporal_load(csr_ea + 2 * (size_t)qbc + 1);
        float xa = xl[(size_t)sa * 64 + c];
        float xb = xl[(size_t)sb * 64 + c];
        step(xa, ea0, ea1, qa < p1);
        step(xb, eb0, eb1, qb < p1);
    }
    // merge across the two halves (each half holds state for the same channel c)
    float mxo = __shfl_xor(mx, 32);
    float deno = __shfl_xor(den, 32);
    float acco = __shfl_xor(acc, 32);
    float nm = fmaxf(mx, mxo);
    float sc = __expf(mx - nm), sco = __expf(mxo - nm);
    den = den * sc + deno * sco;
    acc = acc * sc + acco * sco;

    if (eh == 0) {
        float o = acc / den + bias[c];
        if (relu) o = lrelu(o, 0.01f);
        out[(size_t)d * 64 + c] = o;
    }
}

// ---------------- final two H=16,C=1 layers fused ----------------
// half-wave per dst: lanes 0-15 = f (-> fin), 16-31 = s (-> mus).
__launch_bounds__(256)
__global__ void k_gat_final(const float* __restrict__ packed,
                            const int* __restrict__ row_ptr, const int* __restrict__ csr_src,
                            const float* __restrict__ csr_ea,
                            const float* __restrict__ fWe, const float* __restrict__ sWe,
                            const float* __restrict__ fatt, const float* __restrict__ satt,
                            const float* __restrict__ fbias, const float* __restrict__ sbias,
                            float* __restrict__ fin, float* __restrict__ mus, int n) {
    int hw = (blockIdx.x * blockDim.x + threadIdx.x) >> 5;
    if (hw >= n) return;
    int l = threadIdx.x & 31;
    int hh = l & 15, sel = l >> 4;
    const int d = hw;
    const int p0 = row_ptr[d], p1 = row_ptr[d + 1];
    const float* We = sel ? sWe : fWe;
    float we0 = We[hh], we1 = We[16 + hh];
    float av = (sel ? satt : fatt)[hh];
    float xrv = packed[(size_t)d * 64 + 32 + sel * 16 + hh];
    int xli = sel * 16 + hh;

    float mx[2] = {-3.0e38f, -3.0e38f};
    float den[2] = {0.f, 0.f};
    float acc[2] = {0.f, 0.f};

    auto step = [&](float xv, float2 ea, bool valid, int cc) {
        float t = lrelu(xv + xrv + ea.x * we0 + ea.y * we1, 0.2f) * av;
        if (!valid) t = -__builtin_inff();
        float nm = fmaxf(mx[cc], t);
        float sc = __expf(mx[cc] - nm), w = __expf(t - nm);
        den[cc] = den[cc] * sc + w;
        acc[cc] = acc[cc] * sc + w * xv;
        mx[cc] = nm;
    };

    for (int p = p0; p < p1; p += 4) {
        int q[4], s[4];
        float2 ev[4];
        float xv[4];
#pragma unroll
        for (int u = 0; u < 4; ++u) q[u] = min(p + u, p1 - 1);
#pragma unroll
        for (int u = 0; u < 4; ++u) s[u] = csr_src[q[u]];
#pragma unroll
        for (int u = 0; u < 4; ++u) ev[u] = *(const float2*)(csr_ea + 2 * (size_t)q[u]);
#pragma unroll
        for (int u = 0; u < 4; ++u) xv[u] = packed[(size_t)s[u] * 64 + xli];
#pragma unroll
        for (int u = 0; u < 4; ++u) step(xv[u], ev[u], p + u < p1, u & 1);
    }
    float nm = fmaxf(mx[0], mx[1]);
    float s0 = __expf(mx[0] - nm), s1 = __expf(mx[1] - nm);
    float val = (acc[0] * s0 + acc[1] * s1) / (den[0] * s0 + den[1] * s1);
#pragma unroll
    for (int w = 1; w < 16; w <<= 1) val += __shfl_xor(val, w);
    if ((threadIdx.x & 15) == 0) {
        float o = val * (1.f / 16.f) + (sel ? sbias[0] : fbias[0]);
        if (sel) mus[d] = o; else fin[d] = o;
    }
}

// ---------------- batchnorm ----------------

__global__ void k_bnstats(const float* __restrict__ h, double* __restrict__ stats, int n) {
    int c = threadIdx.x & 63;
    int s0 = blockIdx.x * (blockDim.x >> 6) + (threadIdx.x >> 6);
    int ns = gridDim.x * (blockDim.x >> 6);
    double s = 0.0, s2 = 0.0;
    for (int i = s0; i < n; i += ns) {
        float v = h[(size_t)i * 64 + c];
        s += v;
        s2 += (double)v * v;
    }
    atomicAdd(&stats[c], s);
    atomicAdd(&stats[64 + c], s2);
}

__global__ void k_bnapply(float* __restrict__ h, const double* __restrict__ stats,
                          const float* __restrict__ gamma, const float* __restrict__ beta, int n) {
    int idx = blockIdx.x * blockDim.x + threadIdx.x;
    if (idx >= n * 64) return;
    int c = idx & 63;
    double mu = stats[c] / n;
    double var = stats[64 + c] / n - mu * mu;
    float rs = (float)(1.0 / sqrt(var + 1e-5));
    float v = (h[idx] - (float)mu) * rs * gamma[c] + beta[c];
    h[idx] = lrelu(v, 0.01f);
}

// ---------------- graph-level mean over masked nodes ----------------

__global__ void k_sat_acc(const float* __restrict__ fin, const int* __restrict__ mask,
                          const int* __restrict__ batch,
                          float* __restrict__ sums, float* __restrict__ cnts, int n) {
    int i = blockIdx.x * blockDim.x + threadIdx.x;
    int lane = threadIdx.x & 63;
    int g = (i < n) ? batch[i] : -1;
    float c = (i < n && mask[i] == 0) ? 1.f : 0.f;
    float v = (c > 0.f) ? fin[i] : 0.f;
#pragma unroll
    for (int off = 1; off < 64; off <<= 1) {
        float v2 = __shfl_down(v, off);
        float c2 = __shfl_down(c, off);
        int g2 = __shfl_down(g, off);
        if (lane + off < 64 && g2 == g) { v += v2; c += c2; }
    }
    int gprev = __shfl_up(g, 1);
    bool head = (lane == 0) || (gprev != g);
    if (head && g >= 0 && c > 0.f) {
        atomicAdd(&sums[g], v);
        atomicAdd(&cnts[g], c);
    }
}

__global__ void k_sat_fin(const float* __restrict__ sums, const float* __restrict__ cnts,
                          float* __restrict__ out, int g) {
    int i = threadIdx.x;
    if (i < g) out[i] = sums[i] / fmaxf(cnts[i], 1.f);
}

// ---------------- host ----------------

extern "C" void kernel_launch(void* const* d_in, const int* in_sizes, int n_in,
                              void* d_out, int out_size, void* d_ws, size_t ws_size,
                              hipStream_t stream) {
    const float* x = (const float*)d_in[0];
    const float* eat = (const float*)d_in[1];
    const int* ei = (const int*)d_in[2];
    const int* mask = (const int*)d_in[3];
    const int* batch = (const int*)d_in[4];
    const float* g0_Wl = (const float*)d_in[5];
    const float* g0_bl = (const float*)d_in[6];
    const float* g0_Wr = (const float*)d_in[7];
    const float* g0_br = (const float*)d_in[8];
    const float* g0_We = (const float*)d_in[9];
    const float* g0_att = (const float*)d_in[10];
    const float* g0_bias = (const float*)d_in[11];
    const float* bn_g = (const float*)d_in[12];
    const float* bn_b = (const float*)d_in[13];
    const float* m_Wl = (const float*)d_in[14];
    const float* m_bl = (const float*)d_in[15];
    const float* m_Wr = (const float*)d_in[16];
    const float* m_br = (const float*)d_in[17];
    const float* m_We = (const float*)d_in[18];
    const float* m_att = (const float*)d_in[19];
    const float* m_bias = (const float*)d_in[20];
    const float* f_Wl = (const float*)d_in[21];
    const float* f_bl = (const float*)d_in[22];
    const float* f_Wr = (const float*)d_in[23];
    const float* f_br = (const float*)d_in[24];
    const float* f_We = (const float*)d_in[25];
    const float* f_att = (const float*)d_in[26];
    const float* f_bias = (const float*)d_in[27];
    const float* s_Wl = (const float*)d_in[28];
    const float* s_bl = (const float*)d_in[29];
    const float* s_Wr = (const float*)d_in[30];
    const float* s_br = (const float*)d_in[31];
    const float* s_We = (const float*)d_in[32];
    const float* s_att = (const float*)d_in[33];
    const float* s_bias = (const float*)d_in[34];

    const int N = in_sizes[3];
    const int E = in_sizes[1] / 2;
    const int G = out_size - N;
    const int ITER = in_sizes[14] / 4096;
    const int ET = E + N;
    const int* srcp = ei;
    const int* dstp = ei + E;

    char* wsb = (char*)d_ws;
    size_t off = 0;
    auto alloc = [&](size_t b) { void* p = wsb + off; off = (off + b + 255) & ~(size_t)255; return p; };
    int* cnt = (int*)alloc((size_t)N * 4);
    double* stats = (double*)alloc(128 * 8);
    float* sums = (float*)alloc((size_t)G * 4);
    float* cnts = (float*)alloc((size_t)G * 4);
    size_t zero_bytes = off;
    int* rank = (int*)alloc((size_t)E * 4);
    int* row_ptr = (int*)alloc((size_t)(N + 1) * 4);
    int* csr_src = (int*)alloc((size_t)ET * 4);
    float* csr_ea = (float*)alloc((size_t)ET * 8);
    float* xl = (float*)alloc((size_t)N * 256);
    float* xr = (float*)alloc((size_t)N * 256);
    float* hbuf = (float*)alloc((size_t)N * 256);
    float* fin = (float*)alloc((size_t)N * 4);
    (void)ws_size; (void)n_in;

    float* outv = (float*)d_out;  // [0,N) = mus, [N,N+G) = sat

    hipMemsetAsync(d_ws, 0, zero_bytes, stream);
    const int tb = 256;
    const int gat_grid = (N * 64 + tb - 1) / tb;
    k_degree<<<(E + tb - 1) / tb, tb, 0, stream>>>(dstp, cnt, rank, E);
    k_rowptr<<<1, 1024, 0, stream>>>(cnt, row_ptr, N);
    k_scatter<<<(E + tb - 1) / tb, tb, 0, stream>>>(srcp, dstp, eat, rank, row_ptr, csr_src, csr_ea, E);
    k_selfloop<<<(N + tb - 1) / tb, tb, 0, stream>>>(row_ptr, csr_src, csr_ea, N);

    k_proj0<<<(N * 64 + tb - 1) / tb, tb, 0, stream>>>(x, g0_Wl, g0_bl, g0_Wr, g0_br, xl, xr, N);
    k_gat_h<<<gat_grid, tb, 0, stream>>>(xl, xr, row_ptr, csr_src, csr_ea,
                                         g0_We, g0_att, g0_bias, hbuf, N, 0, 0);
    k_gat_h<<<gat_grid, tb, 0, stream>>>(xl, xr, row_ptr, csr_src, csr_ea,
                                         g0_We, g0_att, g0_bias, hbuf, N, 0, 32);
    k_bnstats<<<128, 256, 0, stream>>>(hbuf, stats, N);
    k_bnapply<<<(N * 64 + tb - 1) / tb, tb, 0, stream>>>(hbuf, stats, bn_g, bn_b, N);

    int gp = (N + 127) / 128;
    for (int l = 0; l < ITER; ++l) {
        k_proj64<<<gp, 256, 0, stream>>>(hbuf, m_Wl + (size_t)l * 4096, m_bl + l * 64,
                                         m_Wr + (size_t)l * 4096, m_br + l * 64, xl, xr, N);
        k_gat_h<<<gat_grid, tb, 0, stream>>>(xl, xr, row_ptr, csr_src, csr_ea,
                                             m_We + l * 128, m_att + l * 64,
                                             m_bias + l * 64, hbuf, N, 1, 0);
        k_gat_h<<<gat_grid, tb, 0, stream>>>(xl, xr, row_ptr, csr_src, csr_ea,
                                             m_We + l * 128, m_att + l * 64,
                                             m_bias + l * 64, hbuf, N, 1, 32);
    }
    k_proj_final<<<(N + 255) / 256, 256, 0, stream>>>(hbuf, f_Wl, f_bl, f_Wr, f_br,
                                                      s_Wl, s_bl, s_Wr, s_br, xl, N);
    k_gat_final<<<(N * 32 + tb - 1) / tb, tb, 0, stream>>>(xl, row_ptr, csr_src, csr_ea,
                                                           f_We, s_We, f_att, s_att,
                                                           f_bias, s_bias, fin, outv, N);
    k_sat_acc<<<(N + tb - 1) / tb, tb, 0, stream>>>(fin, mask, batch, sums, cnts, N);
    k_sat_fin<<<1, 64, 0, stream>>>(sums, cnts, outv + N, G);
}